// Round 1
// baseline (263.711 us; speedup 1.0000x reference)
//
#include <hip/hip_runtime.h>
#include <cmath>

typedef unsigned short u16;
typedef unsigned int u32;
typedef __bf16 bf16x8 __attribute__((ext_vector_type(8)));
typedef float  floatx4 __attribute__((ext_vector_type(4)));
typedef float  floatx16 __attribute__((ext_vector_type(16)));
typedef unsigned int u32x4 __attribute__((ext_vector_type(4)));

#define T_DIM 2048
#define E_DIM 1024
#define H_DIM 16
#define HD    64
#define M_DIM 8192                    // B*T
#define NE    8388608                 // M*E  (also B*H*T*HD)
#define E2    1048576                 // E*E
#define QSCALE 0.18033688f            // 0.125 * log2(e): logits in exp2 domain

// float -> bf16 (RNE)
__device__ __forceinline__ u16 f2bf(float f) {
    unsigned u = __builtin_bit_cast(unsigned, f);
    return (u16)((u + 0x7FFFu + ((u >> 16) & 1u)) >> 16);
}
// two floats -> packed bf16x2
__device__ __forceinline__ u32 pack2bf(float f0, float f1) {
    u32 a0 = __builtin_bit_cast(u32, f0) + 0x8000u;
    u32 a1 = __builtin_bit_cast(u32, f1) + 0x8000u;
    return __builtin_amdgcn_perm(a1, a0, 0x07060302u);  // low16=bf(f0), high16=bf(f1)
}

// async global->LDS, 16B per lane. lds base wave-uniform; HW adds lane*16.
__device__ __forceinline__ void gl_lds16(const u16* g, const u16* l) {
    __builtin_amdgcn_global_load_lds(
        (const __attribute__((address_space(1))) void*)g,
        (__attribute__((address_space(3))) void*)l,
        16, 0, 0);
}

__device__ __forceinline__ bf16x8 ld_frag(const u16* p) {
    return *(const bf16x8*)p;
}

#define S_BARRIER()  asm volatile("s_barrier" ::: "memory")
#define WAIT_LGKM0() asm volatile("s_waitcnt lgkmcnt(0)" ::: "memory")

// ---------------------------------------------------------------------------
// x fp32 -> bf16, 8 elems/thread
// ---------------------------------------------------------------------------
__global__ void cvt_x_kernel(const float* __restrict__ x, u16* __restrict__ xb) {
    const size_t i = (size_t)blockIdx.x * 256 + threadIdx.x;
    const float4* s = (const float4*)x + i * 2;
    const float4 a = s[0], b = s[1];
    u16 v[8] __attribute__((aligned(16)));
    v[0]=f2bf(a.x); v[1]=f2bf(a.y); v[2]=f2bf(a.z); v[3]=f2bf(a.w);
    v[4]=f2bf(b.x); v[5]=f2bf(b.y); v[6]=f2bf(b.z); v[7]=f2bf(b.w);
    *(uint4*)(xb + i * 8) = *(const uint4*)v;
}

// ---------------------------------------------------------------------------
// W [K,N] fp32 -> Wt [N,K] bf16 (transpose+convert), 64x64 tiles.
// ---------------------------------------------------------------------------
__global__ void transpose_cvt_kernel(const float* __restrict__ w0, const float* __restrict__ w1,
                                     const float* __restrict__ w2, const float* __restrict__ w3,
                                     u16* __restrict__ out) {
    __shared__ u16 tile[64][65];
    const float* W = blockIdx.z == 0 ? w0 : blockIdx.z == 1 ? w1 : blockIdx.z == 2 ? w2 : w3;
    u16* O = out + (size_t)blockIdx.z * E2;
    const int k0 = blockIdx.y * 64, n0 = blockIdx.x * 64;
    const int r = threadIdx.x >> 2, cp = (threadIdx.x & 3) * 16;
    const float4* src = (const float4*)&W[(size_t)(k0 + r) * E_DIM + n0 + cp];
    #pragma unroll
    for (int j4 = 0; j4 < 4; ++j4) {
        const float4 f = src[j4];
        tile[r][cp + j4*4 + 0] = f2bf(f.x);
        tile[r][cp + j4*4 + 1] = f2bf(f.y);
        tile[r][cp + j4*4 + 2] = f2bf(f.z);
        tile[r][cp + j4*4 + 3] = f2bf(f.w);
    }
    __syncthreads();
    u16 vals[16] __attribute__((aligned(16)));
    #pragma unroll
    for (int j = 0; j < 16; ++j) vals[j] = tile[cp + j][r];
    u16* dst = &O[(size_t)(n0 + r) * E_DIM + k0 + cp];
    *(uint4*)dst       = *(const uint4*)vals;
    *(uint4*)(dst + 8) = *(const uint4*)(vals + 8);
}

// ---------------------------------------------------------------------------
// 256x256 8-phase bf16 MFMA GEMM (T2+T3+T4+T5): out = A @ Bt^T + bias.
//
// BM=BN=256, BK=64, 512 threads = 8 waves (2M x 4N), per-wave 128x64 out.
// LDS 128 KiB: A[2 slot][2 unit][128 row][64 col] bf16, B identical at +64KiB.
//   A unit u rows: global tile row = (ur>>6)*128 + u*64 + (ur&63)
//   B unit u rows: global tile row = (ur>>5)*64  + u*32 + (ur&31)
//   (so each unit is exactly the rows one wave-half / N-quadrant reads)
// Chunk-XOR swizzle: 16B chunk slot = chunk ^ (row&7)  (8 chunks per 128B row),
//   applied to the global SOURCE address (global_load_lds dest must be linear)
//   and to the ds_read address -> conflict-free b128 reads.
// Per K-tile (BK=64): 4 phases, each {ds_read subtile | stage 1 half-tile ->
//   s_barrier -> lgkmcnt(0) -> setprio(1) -> 16 MFMA -> setprio(0) -> s_barrier}.
// Region schedule (tile t, slot s=t&1): reads A0@P1 B0@P1 B1@P2 A1@P3;
//   stages B1(t+1)@P1 [slot 1-s], A0(t+2)@P2, B0(t+2)@P3, A1(t+2)@P4 [slot s,
//   each >=1 barrier after that region's last read].
// vmcnt(6) once per K-tile at P4 (3 half-tiles = 6 loads stay in flight);
//   vmcnt(0) only at tile NT-2; all barriers/waits are asm w/ memory clobber
//   so no load crosses a phase boundary.
// REMAP 0: fp32 out (out-proj). REMAP 1: bf16 q/k head-split (+QSCALE on q)
//   and V^T -> vt[bh][d][t] packed uint2.
// ---------------------------------------------------------------------------
#define NT 16   // K / BK = 1024 / 64

#define MFMA16(F0, N0, BQ)                                                          \
    _Pragma("unroll") for (int kk = 0; kk < 2; ++kk)                                \
    _Pragma("unroll") for (int mi = 0; mi < 4; ++mi)                                \
    _Pragma("unroll") for (int ni = 0; ni < 2; ++ni)                                \
        acc[(F0)+mi][(N0)+ni] = __builtin_amdgcn_mfma_f32_16x16x32_bf16(            \
            Aq[mi][kk], BQ[ni][kk], acc[(F0)+mi][(N0)+ni], 0, 0, 0);

template<int REMAP>
__global__ __launch_bounds__(512, 2)
void gemm256_kernel(const u16* __restrict__ A, const u16* __restrict__ Bt,
                    const float* __restrict__ bias0, const float* __restrict__ bias1,
                    const float* __restrict__ bias2, void* __restrict__ outp,
                    u16* __restrict__ vtp)
{
    __shared__ u16 SM[65536];      // 128 KiB: A = SM[0..32767], B = SM[32768..]
    const int tid = threadIdx.x;
    const int w = tid >> 6, lane = tid & 63, quad = lane >> 4, l15 = lane & 15;
    const int wm = w >> 2, wn = w & 3;

    // XCD-chunked block swizzle (gridDim.x % 8 == 0: 384 / 128)
    const int nbx = (REMAP == 1) ? 12 : 4;
    const int cpx = gridDim.x >> 3;
    const int swz = ((int)blockIdx.x & 7) * cpx + ((int)blockIdx.x >> 3);
    const int bx = swz % nbx, by = swz / nbx;
    const int r0 = by * 256, c0 = bx * 256;

    // staging precompute: 2 x gl_lds16 per thread per 16KiB unit
    const u16* pA[2]; const u16* pB[2]; unsigned lb[2];
    #pragma unroll
    for (int i = 0; i < 2; ++i) {
        const int L = i * 512 + tid, ur = L >> 3, sl = L & 7, c = sl ^ (ur & 7);
        const int ra = ((ur >> 6) << 7) + (ur & 63);
        const int nb = ((ur >> 5) << 6) + (ur & 31);
        pA[i] = A  + (size_t)(r0 + ra) * E_DIM + c * 8;
        pB[i] = Bt + (size_t)(c0 + nb) * E_DIM + c * 8;
        lb[i] = i * 8192u + (unsigned)w * 1024u;
    }
    auto stageA = [&](int kt, int u) {            // kt = absolute target tile
        #pragma unroll
        for (int i = 0; i < 2; ++i) {
            const unsigned off = __builtin_amdgcn_readfirstlane(
                (unsigned)(kt & 1) * 32768u + (unsigned)u * 16384u + lb[i]);
            gl_lds16(pA[i] + u * (64 * E_DIM) + kt * 64,
                     (const u16*)((const char*)SM + off));
        }
    };
    auto stageB = [&](int kt, int u) {
        #pragma unroll
        for (int i = 0; i < 2; ++i) {
            const unsigned off = __builtin_amdgcn_readfirstlane(
                65536u + (unsigned)(kt & 1) * 32768u + (unsigned)u * 16384u + lb[i]);
            gl_lds16(pB[i] + u * (32 * E_DIM) + kt * 64,
                     (const u16*)((const char*)SM + off));
        }
    };

    // fragment read offsets (u16 units); kk=1 flips chunk bit2 -> ^32 u16
    const int arow = (wm * 64 + l15) * 64;
    const int brow = (wn * 32 + l15) * 64;
    const int sl0  = (quad ^ (l15 & 7)) * 8;

    floatx4 acc[8][4];
    #pragma unroll
    for (int f = 0; f < 8; ++f)
        #pragma unroll
        for (int n = 0; n < 4; ++n) acc[f][n] = (floatx4){0.f, 0.f, 0.f, 0.f};

    bf16x8 Aq[4][2], Bq0[2][2], Bq1[2][2];

    // prologue: tile0 all 4 units + tile1 {A0,B0,A1}; B1(1) is staged at kt=0 P1.
    // vmcnt(6) -> tile0 landed, tile1's 3 units in flight (steady-state invariant).
    stageA(0, 0); stageB(0, 0); stageA(0, 1); stageB(0, 1);
    stageA(1, 0); stageB(1, 0); stageA(1, 1);
    asm volatile("s_waitcnt vmcnt(6)" ::: "memory");
    S_BARRIER();

    for (int kt = 0; kt < NT; ++kt) {
        const unsigned Ab = (unsigned)(kt & 1) * 16384u;
        const unsigned Bb = 32768u + (unsigned)(kt & 1) * 16384u;

        // ---- P1: read A-half0 (8) + B-half0 (4); stage B1(kt+1) [other slot]
        #pragma unroll
        for (int mi = 0; mi < 4; ++mi) {
            Aq[mi][0] = ld_frag(&SM[Ab + arow + mi * 1024 + sl0]);
            Aq[mi][1] = ld_frag(&SM[Ab + arow + mi * 1024 + (sl0 ^ 32)]);
        }
        #pragma unroll
        for (int ni = 0; ni < 2; ++ni) {
            Bq0[ni][0] = ld_frag(&SM[Bb + brow + ni * 1024 + sl0]);
            Bq0[ni][1] = ld_frag(&SM[Bb + brow + ni * 1024 + (sl0 ^ 32)]);
        }
        if (kt + 1 < NT) stageB(kt + 1, 1);
        S_BARRIER(); WAIT_LGKM0();
        __builtin_amdgcn_s_setprio(1);
        MFMA16(0, 0, Bq0)
        __builtin_amdgcn_s_setprio(0);
        S_BARRIER();

        // ---- P2: read B-half1 (4); stage A0(kt+2) [slot s, A0 last read P1]
        #pragma unroll
        for (int ni = 0; ni < 2; ++ni) {
            Bq1[ni][0] = ld_frag(&SM[Bb + 8192 + brow + ni * 1024 + sl0]);
            Bq1[ni][1] = ld_frag(&SM[Bb + 8192 + brow + ni * 1024 + (sl0 ^ 32)]);
        }
        if (kt + 2 < NT) stageA(kt + 2, 0);
        S_BARRIER(); WAIT_LGKM0();
        __builtin_amdgcn_s_setprio(1);
        MFMA16(0, 2, Bq1)
        __builtin_amdgcn_s_setprio(0);
        S_BARRIER();

        // ---- P3: read A-half1 (8, reuse Aq); stage B0(kt+2) [B0 last read P1]
        #pragma unroll
        for (int mi = 0; mi < 4; ++mi) {
            Aq[mi][0] = ld_frag(&SM[Ab + 8192 + arow + mi * 1024 + sl0]);
            Aq[mi][1] = ld_frag(&SM[Ab + 8192 + arow + mi * 1024 + (sl0 ^ 32)]);
        }
        if (kt + 2 < NT) stageB(kt + 2, 0);
        S_BARRIER(); WAIT_LGKM0();
        __builtin_amdgcn_s_setprio(1);
        MFMA16(4, 2, Bq1)
        __builtin_amdgcn_s_setprio(0);
        S_BARRIER();

        // ---- P4: no reads; stage A1(kt+2) [A1 last read P3]; counted vmcnt
        if (kt + 2 < NT) stageA(kt + 2, 1);
        S_BARRIER();
        __builtin_amdgcn_s_setprio(1);
        MFMA16(4, 0, Bq0)
        __builtin_amdgcn_s_setprio(0);
        if (kt < NT - 2)       asm volatile("s_waitcnt vmcnt(6)" ::: "memory");
        else if (kt == NT - 2) asm volatile("s_waitcnt vmcnt(0)" ::: "memory");
        S_BARRIER();
    }

    // epilogue: row = r0 + wm*128 + f*16 + quad*4 + r ; col = c0 + wn*64 + n*16 + l15
    #pragma unroll
    for (int n = 0; n < 4; ++n) {
        const int col = c0 + wn * 64 + n * 16 + l15;
        if (REMAP == 1) {
            const int which = col >> 10, cc = col & 1023;
            const float* bp_ = which == 0 ? bias0 : which == 1 ? bias1 : bias2;
            const float bv = bp_[cc];
            const int h = cc >> 6, d = cc & 63;
            #pragma unroll
            for (int f = 0; f < 8; ++f) {
                const int row0 = r0 + wm * 128 + f * 16 + quad * 4;
                const int b = row0 >> 11, t0 = row0 & (T_DIM - 1);
                if (which == 2) {
                    // V^T: vt[bh][d][t], 4 consecutive t -> one uint2 store
                    uint2 pk;
                    pk.x = pack2bf(acc[f][n][0] + bv, acc[f][n][1] + bv);
                    pk.y = pack2bf(acc[f][n][2] + bv, acc[f][n][3] + bv);
                    *(uint2*)&vtp[((size_t)((b * H_DIM + h) * HD + d)) * T_DIM + t0] = pk;
                } else {
                    #pragma unroll
                    for (int r = 0; r < 4; ++r) {
                        float val = acc[f][n][r] + bv;
                        if (which == 0) val *= QSCALE;
                        ((u16*)outp)[(size_t)which * NE +
                            (((size_t)(b * H_DIM + h) * T_DIM + (t0 + r)) * HD + d)] = f2bf(val);
                    }
                }
            }
        } else {
            const float bv = bias0[col];
            #pragma unroll
            for (int f = 0; f < 8; ++f) {
                #pragma unroll
                for (int r = 0; r < 4; ++r) {
                    const int row = r0 + wm * 128 + f * 16 + quad * 4 + r;
                    ((float*)outp)[(size_t)row * E_DIM + col] = acc[f][n][r] + bv;
                }
            }
        }
    }
}

// ---------------------------------------------------------------------------
// MFMA flash attention v6 (verified, unchanged): 32x32x16 MFMA, no P LDS
// round-trip (lane^32 exchange), max-free softmax, double-buffered K/V staging
// with XOR swizzles.
// ---------------------------------------------------------------------------
__global__ __launch_bounds__(256, 2)
void attn_kernel(const u16* __restrict__ q, const u16* __restrict__ k,
                 const u16* __restrict__ vt, u16* __restrict__ y)
{
    __shared__ u16 Ks[2][128 * 64];   // [key][d], 8 chunks/row, XOR-swizzled
    __shared__ u16 Vs[2][64 * 128];   // [d][key], 16 chunks/row, swizzled

    const int tid = threadIdx.x;
    const int w = tid >> 6, lane = tid & 63;
    const int hl = lane >> 5, l31 = lane & 31, l7 = lane & 7;
    const int bh = blockIdx.x;                    // XCD = bh % 8
    const int qt = gridDim.y - 1 - blockIdx.y;    // heavy q-blocks dispatch first
    const int q0 = qt * 128;
    const int b = bh >> 4, h = bh & (H_DIM - 1);
    const size_t qkb = (size_t)bh * (T_DIM * HD);
    const size_t vtb = (size_t)bh * (HD * T_DIM);

    // Q as B-operand: lane holds Q[d = kc*16 + hl*8 + j][query = q0+w*32+l31]
    const int qrow = q0 + w * 32 + l31;
    bf16x8 Qf[4];
    #pragma unroll
    for (int kc = 0; kc < 4; ++kc)
        Qf[kc] = ld_frag(&q[qkb + (size_t)qrow * HD + kc * 16 + hl * 8]);

    float rsum = 0.f;                 // row sum for query l31 (half-wave partial)
    floatx16 O[2];
    #pragma unroll
    for (int i = 0; i < 16; ++i) { O[0][i] = 0.f; O[1][i] = 0.f; }

    // stage K/V tile jt into buffer sel (async; fenced by next __syncthreads)
    auto stage = [&](int jt, int sel) {
        const int j0 = jt * 128;
        #pragma unroll
        for (int i = 0; i < 4; ++i) {
            const int L = i * 256 + tid;
            const unsigned off = __builtin_amdgcn_readfirstlane(i * 4096 + w * 1024);
            {   const int row = L >> 3, ch = (L & 7) ^ (row & 7);
                gl_lds16(&k[qkb + (size_t)(j0 + row) * HD + ch * 8],
                         (u16*)((char*)&Ks[sel][0] + off)); }
            {   const int row = L >> 4, ch = (L & 15) ^ (row & 7);
                gl_lds16(&vt[vtb + (size_t)row * T_DIM + j0 + ch * 8],
                         (u16*)((char*)&Vs[sel][0] + off)); }
        }
    };

    stage(0, 0);
    for (int jt = 0; jt <= qt; ++jt) {
        __syncthreads();                       // drains stage(jt)
        if (jt < qt) stage(jt + 1, (jt + 1) & 1);
        const u16* const Kb = &Ks[jt & 1][0];
        const u16* const Vb = &Vs[jt & 1][0];

        const bool diag = (jt == qt);
        const int nkg = diag ? (w + 1) : 4;    // active 32-key groups

        #pragma unroll
        for (int kg = 0; kg < 4; ++kg) {
            if (kg < nkg) {
                // S^T = K_kg @ Q : D[key=(reg&3)+8*(reg>>2)+4*hl][query=l31]
                floatx16 S;
                #pragma unroll
                for (int i = 0; i < 16; ++i) S[i] = 0.f;
                const int krow = kg * 32 + l31;
                #pragma unroll
                for (int kc = 0; kc < 4; ++kc) {
                    const int ch = (kc * 2 + hl) ^ l7;      // krow&7 == l7
                    S = __builtin_amdgcn_mfma_f32_32x32x16_bf16(
                            ld_frag(&Kb[krow * 64 + ch * 8]), Qf[kc], S, 0, 0, 0);
                }

                // exp2 (+ causal mask on boundary group), rsum, pack
                const bool bnd = diag && (kg == w);
                u32 u[8], ru[8];
                #pragma unroll
                for (int i = 0; i < 8; ++i) {
                    const int row0 = (2*i & 3) + 8 * (i >> 1) + 4 * hl;
                    float p0 = __builtin_amdgcn_exp2f(S[2*i]);
                    float p1 = __builtin_amdgcn_exp2f(S[2*i + 1]);
                    if (bnd && (row0     > l31)) p0 = 0.f;
                    if (bnd && (row0 + 1 > l31)) p1 = 0.f;
                    rsum += p0 + p1;
                    u[i] = pack2bf(p0, p1);
                }
                // lane^32 exchange: build PV A-frags (m=query=l31, k=keys)
                #pragma unroll
                for (int i = 0; i < 8; ++i) ru[i] = __shfl_xor(u[i], 32, 64);
                const u32x4 f0 = hl ? (u32x4){ru[2], ru[3], u[2], u[3]}
                                    : (u32x4){u[0], u[1], ru[0], ru[1]};
                const u32x4 f1 = hl ? (u32x4){ru[6], ru[7], u[6], u[7]}
                                    : (u32x4){u[4], u[5], ru[4], ru[5]};

                // O[dh] += P_chunk @ V  (B: lane = V[key=8*kc16+j][d=dh*32+l31])
                #pragma unroll
                for (int c2 = 0; c2 < 2; ++c2) {
                    const bf16x8 Pf = __builtin_bit_cast(bf16x8, c2 ? f1 : f0);
                    const int kc16 = kg * 4 + c2 * 2 + hl;
                    #pragma unroll
                    for (int dh = 0; dh < 2; ++dh) {
                        const int d = dh * 32 + l31;
                        const int ch = kc16 ^ l7;           // d&7 == l7
                        O[dh] = __builtin_amdgcn_mfma_f32_32x32x16_bf16(
                                    Pf, ld_frag(&Vb[d * 128 + ch * 8]), O[dh], 0, 0, 0);
                    }
                }
            }
        }
    }

    // epilogue: complete row sums (halves), normalize, store merged heads
    rsum += __shfl_xor(rsum, 32, 64);
    const float linv = 1.0f / rsum;            // for query l31
    #pragma unroll
    for (int i = 0; i < 16; ++i) {
        const int qr = (i & 3) + 8 * (i >> 2) + 4 * hl;    // query row of reg i
        const float lq = __shfl(linv, qr, 32);
        const int t = q0 + w * 32 + qr;
        const size_t base = ((size_t)(b * T_DIM + t)) * E_DIM + h * HD;
        y[base + l31]      = f2bf(O[0][i] * lq);
        y[base + 32 + l31] = f2bf(O[1][i] * lq);
    }
}

extern "C" void kernel_launch(void* const* d_in, const int* in_sizes, int n_in,
                              void* d_out, int out_size, void* d_ws, size_t ws_size,
                              hipStream_t stream)
{
    const float* x  = (const float*)d_in[0];
    const float* Wq = (const float*)d_in[2];
    const float* bq = (const float*)d_in[3];
    const float* Wk = (const float*)d_in[4];
    const float* bk = (const float*)d_in[5];
    const float* Wv = (const float*)d_in[6];
    const float* bv = (const float*)d_in[7];
    const float* Wp = (const float*)d_in[8];
    const float* bp = (const float*)d_in[9];

    u16* xb  = (u16*)d_ws;          // NE
    u16* wt  = xb + NE;             // 4*E2
    u16* qb  = wt + 4 * (size_t)E2; // NE (q) ; k at qb+NE
    u16* kb  = qb + NE;             // NE
    u16* vtb = kb + NE;             // NE  (V^T, written by the QKV GEMM)
    u16* yb  = vtb + NE;            // NE

    cvt_x_kernel<<<NE / (256 * 8), 256, 0, stream>>>(x, xb);
    transpose_cvt_kernel<<<dim3(16, 16, 4), 256, 0, stream>>>(Wq, Wk, Wv, Wp, wt);
    gemm256_kernel<1><<<384, 512, 0, stream>>>(xb, wt, bq, bk, bv, qb, vtb);
    attn_kernel<<<dim3(64, 16), 256, 0, stream>>>(qb, kb, vtb, yb);
    gemm256_kernel<0><<<128, 512, 0, stream>>>(yb, wt + 3 * (size_t)E2, bp, bp, bp, (float*)d_out, nullptr);
}

// Round 2
// 247.999 us; speedup vs baseline: 1.0634x; 1.0634x over previous
//
#include <hip/hip_runtime.h>
#include <cmath>

typedef unsigned short u16;
typedef unsigned int u32;
typedef __bf16 bf16x8 __attribute__((ext_vector_type(8)));
typedef float  floatx4 __attribute__((ext_vector_type(4)));
typedef float  floatx16 __attribute__((ext_vector_type(16)));
typedef unsigned int u32x4 __attribute__((ext_vector_type(4)));

#define T_DIM 2048
#define E_DIM 1024
#define H_DIM 16
#define HD    64
#define M_DIM 8192                    // B*T
#define NE    8388608                 // M*E  (also B*H*T*HD)
#define E2    1048576                 // E*E
#define QSCALE 0.18033688f            // 0.125 * log2(e): logits in exp2 domain

// float -> bf16 (RNE)
__device__ __forceinline__ u16 f2bf(float f) {
    unsigned u = __builtin_bit_cast(unsigned, f);
    return (u16)((u + 0x7FFFu + ((u >> 16) & 1u)) >> 16);
}
// two floats -> packed bf16x2
__device__ __forceinline__ u32 pack2bf(float f0, float f1) {
    u32 a0 = __builtin_bit_cast(u32, f0) + 0x8000u;
    u32 a1 = __builtin_bit_cast(u32, f1) + 0x8000u;
    return __builtin_amdgcn_perm(a1, a0, 0x07060302u);  // low16=bf(f0), high16=bf(f1)
}

// async global->LDS, 16B per lane. lds base wave-uniform; HW adds lane*16.
__device__ __forceinline__ void gl_lds16(const u16* g, const u16* l) {
    __builtin_amdgcn_global_load_lds(
        (const __attribute__((address_space(1))) void*)g,
        (__attribute__((address_space(3))) void*)l,
        16, 0, 0);
}

__device__ __forceinline__ bf16x8 ld_frag(const u16* p) {
    return *(const bf16x8*)p;
}

#define S_BARRIER()  asm volatile("s_barrier" ::: "memory")
#define WAIT_LGKM0() asm volatile("s_waitcnt lgkmcnt(0)" ::: "memory")

// ---------------------------------------------------------------------------
// x fp32 -> bf16, 8 elems/thread
// ---------------------------------------------------------------------------
__global__ void cvt_x_kernel(const float* __restrict__ x, u16* __restrict__ xb) {
    const size_t i = (size_t)blockIdx.x * 256 + threadIdx.x;
    const float4* s = (const float4*)x + i * 2;
    const float4 a = s[0], b = s[1];
    u16 v[8] __attribute__((aligned(16)));
    v[0]=f2bf(a.x); v[1]=f2bf(a.y); v[2]=f2bf(a.z); v[3]=f2bf(a.w);
    v[4]=f2bf(b.x); v[5]=f2bf(b.y); v[6]=f2bf(b.z); v[7]=f2bf(b.w);
    *(uint4*)(xb + i * 8) = *(const uint4*)v;
}

// ---------------------------------------------------------------------------
// W [K,N] fp32 -> Wt [N,K] bf16 (transpose+convert), 64x64 tiles.
// ---------------------------------------------------------------------------
__global__ void transpose_cvt_kernel(const float* __restrict__ w0, const float* __restrict__ w1,
                                     const float* __restrict__ w2, const float* __restrict__ w3,
                                     u16* __restrict__ out) {
    __shared__ u16 tile[64][65];
    const float* W = blockIdx.z == 0 ? w0 : blockIdx.z == 1 ? w1 : blockIdx.z == 2 ? w2 : w3;
    u16* O = out + (size_t)blockIdx.z * E2;
    const int k0 = blockIdx.y * 64, n0 = blockIdx.x * 64;
    const int r = threadIdx.x >> 2, cp = (threadIdx.x & 3) * 16;
    const float4* src = (const float4*)&W[(size_t)(k0 + r) * E_DIM + n0 + cp];
    #pragma unroll
    for (int j4 = 0; j4 < 4; ++j4) {
        const float4 f = src[j4];
        tile[r][cp + j4*4 + 0] = f2bf(f.x);
        tile[r][cp + j4*4 + 1] = f2bf(f.y);
        tile[r][cp + j4*4 + 2] = f2bf(f.z);
        tile[r][cp + j4*4 + 3] = f2bf(f.w);
    }
    __syncthreads();
    u16 vals[16] __attribute__((aligned(16)));
    #pragma unroll
    for (int j = 0; j < 16; ++j) vals[j] = tile[cp + j][r];
    u16* dst = &O[(size_t)(n0 + r) * E_DIM + k0 + cp];
    *(uint4*)dst       = *(const uint4*)vals;
    *(uint4*)(dst + 8) = *(const uint4*)(vals + 8);
}

// ---------------------------------------------------------------------------
// 256x128 phase-pipelined bf16 MFMA GEMM: out = A @ Bt^T + bias.
//
// BM=256, BN=128, BK=64, 512 threads = 8 waves (2M x 4N), per-wave 128x32 out.
// Grids are EXACT multiples of 256 CUs (QKV: 768 = 3 rounds; out-proj: 256 = 1
// round) -> zero dispatch tail (round-1's 1.5/0.5-round tail cost ~25-50%).
// LDS 96 KiB: A[2 slot][2 unit][128 r][64 c] (unit u row ur -> global row
//   (ur>>6)*128 + u*64 + (ur&63)), B[2 slot][128 col-row][64] at byte 65536.
// Chunk-XOR swizzle (slot = chunk ^ (row&7)) on global source + ds_read addr.
// Per K-tile, 2 phases of 16 MFMA:
//   P1: rd A-half0 (8 b128) + B (4 b128) | stage A1(kt+1) [other slot]
//       -> bar -> lgkm0 -> prio1 -> 16 MFMA q0 -> prio0 -> vmcnt(6) -> bar
//   P2: rd A-half1 (8)                   | stage A0(kt+2)+B(kt+2) [same slot]
//       -> bar -> lgkm0 -> prio1 -> 16 MFMA q1 -> prio0 -> vmcnt(6|0) -> bar
// Landing proofs: end-P1 vmcnt(6) confirms A1(kt) (oldest 2 of 8 in flight)
// before P2 reads it; end-P2 vmcnt(6) confirms A0/B(kt+1) before next P1.
// Same-slot stages are >=1 barrier after that region's last ds_read.
// REMAP 0: fp32 out (out-proj). REMAP 1: bf16 q/k head-split (+QSCALE on q)
//   and V^T -> vt[bh][d][t] packed uint2.
// ---------------------------------------------------------------------------
#define NT 16   // K / BK = 1024 / 64

#define MFMA_Q(F0)                                                              \
    _Pragma("unroll") for (int kk = 0; kk < 2; ++kk)                            \
    _Pragma("unroll") for (int mi = 0; mi < 4; ++mi)                            \
    _Pragma("unroll") for (int ni = 0; ni < 2; ++ni)                            \
        acc[(F0)+mi][ni] = __builtin_amdgcn_mfma_f32_16x16x32_bf16(             \
            Aq[mi][kk], Bq[ni][kk], acc[(F0)+mi][ni], 0, 0, 0);

template<int REMAP>
__global__ __launch_bounds__(512, 2)
void gemm256_kernel(const u16* __restrict__ A, const u16* __restrict__ Bt,
                    const float* __restrict__ bias0, const float* __restrict__ bias1,
                    const float* __restrict__ bias2, void* __restrict__ outp,
                    u16* __restrict__ vtp)
{
    __shared__ u16 SM[49152];      // 96 KiB
    const int tid = threadIdx.x;
    const int w = tid >> 6, lane = tid & 63, quad = lane >> 4, l15 = lane & 15;
    const int wm = w >> 2, wn = w & 3;

    // XCD-chunked block swizzle (grids 768 / 256, both % 8 == 0)
    const int nbx = (REMAP == 1) ? 24 : 8;
    const int cpx = gridDim.x >> 3;
    const int swz = ((int)blockIdx.x & 7) * cpx + ((int)blockIdx.x >> 3);
    const int bx = swz % nbx, by = swz / nbx;
    const int r0 = by * 256, c0 = bx * 128;

    // staging precompute: 2 x gl_lds16 per thread per 16 KiB unit
    const u16* pA[2]; const u16* pB[2]; unsigned lb[2];
    #pragma unroll
    for (int i = 0; i < 2; ++i) {
        const int L = i * 512 + tid, ur = L >> 3, sl = L & 7, c = sl ^ (ur & 7);
        const int ra = ((ur >> 6) << 7) + (ur & 63);
        pA[i] = A  + (size_t)(r0 + ra) * E_DIM + c * 8;
        pB[i] = Bt + (size_t)(c0 + ur) * E_DIM + c * 8;
        lb[i] = (unsigned)i * 8192u + (unsigned)w * 1024u;
    }
    auto stageA = [&](int kt, int u) {            // unit u of tile kt
        #pragma unroll
        for (int i = 0; i < 2; ++i) {
            const unsigned off = __builtin_amdgcn_readfirstlane(
                (unsigned)(kt & 1) * 32768u + (unsigned)u * 16384u + lb[i]);
            gl_lds16(pA[i] + u * (64 * E_DIM) + kt * 64,
                     (const u16*)((const char*)SM + off));
        }
    };
    auto stageB = [&](int kt) {
        #pragma unroll
        for (int i = 0; i < 2; ++i) {
            const unsigned off = __builtin_amdgcn_readfirstlane(
                65536u + (unsigned)(kt & 1) * 16384u + lb[i]);
            gl_lds16(pB[i] + kt * 64,
                     (const u16*)((const char*)SM + off));
        }
    };

    // fragment read offsets (u16 units); kk=1 flips chunk bit2 -> ^32 u16
    const int arow = (wm * 64 + l15) * 64;
    const int brow = (wn * 32 + l15) * 64;
    const int sl0  = (quad ^ (l15 & 7)) * 8;

    floatx4 acc[8][2];
    #pragma unroll
    for (int f = 0; f < 8; ++f)
        #pragma unroll
        for (int n = 0; n < 2; ++n) acc[f][n] = (floatx4){0.f, 0.f, 0.f, 0.f};

    bf16x8 Aq[4][2], Bq[2][2];

    // prologue: tile0 full (6 loads) + A0(1),B(1) (4 loads); vmcnt(4) -> tile0
    // landed, 4 in flight. Loop invariant: <=6 in flight at each phase end.
    stageA(0, 0); stageA(0, 1); stageB(0);
    stageA(1, 0); stageB(1);
    asm volatile("s_waitcnt vmcnt(4)" ::: "memory");
    S_BARRIER();

    for (int kt = 0; kt < NT; ++kt) {
        const unsigned Ab = (unsigned)(kt & 1) * 16384u;            // u16 idx
        const unsigned Bb = 32768u + (unsigned)(kt & 1) * 8192u;    // u16 idx

        // ---- P1: read A-half0 (unit0) + B; stage A1(kt+1) [other slot]
        #pragma unroll
        for (int mi = 0; mi < 4; ++mi) {
            Aq[mi][0] = ld_frag(&SM[Ab + arow + mi * 1024 + sl0]);
            Aq[mi][1] = ld_frag(&SM[Ab + arow + mi * 1024 + (sl0 ^ 32)]);
        }
        #pragma unroll
        for (int ni = 0; ni < 2; ++ni) {
            Bq[ni][0] = ld_frag(&SM[Bb + brow + ni * 1024 + sl0]);
            Bq[ni][1] = ld_frag(&SM[Bb + brow + ni * 1024 + (sl0 ^ 32)]);
        }
        if (kt + 1 < NT) stageA(kt + 1, 1);
        S_BARRIER(); WAIT_LGKM0();
        __builtin_amdgcn_s_setprio(1);
        MFMA_Q(0)
        __builtin_amdgcn_s_setprio(0);
        asm volatile("s_waitcnt vmcnt(6)" ::: "memory");   // A1(kt) landed
        S_BARRIER();

        // ---- P2: read A-half1 (unit1, reuse Aq); stage A0(kt+2)+B(kt+2)
        #pragma unroll
        for (int mi = 0; mi < 4; ++mi) {
            Aq[mi][0] = ld_frag(&SM[Ab + 8192 + arow + mi * 1024 + sl0]);
            Aq[mi][1] = ld_frag(&SM[Ab + 8192 + arow + mi * 1024 + (sl0 ^ 32)]);
        }
        if (kt + 2 < NT) { stageA(kt + 2, 0); stageB(kt + 2); }
        S_BARRIER(); WAIT_LGKM0();
        __builtin_amdgcn_s_setprio(1);
        MFMA_Q(4)
        __builtin_amdgcn_s_setprio(0);
        if (kt < NT - 2)       asm volatile("s_waitcnt vmcnt(6)" ::: "memory");
        else if (kt == NT - 2) asm volatile("s_waitcnt vmcnt(0)" ::: "memory");
        S_BARRIER();
    }

    // epilogue: row = r0 + wm*128 + f*16 + quad*4 + r ; col = c0 + wn*32 + n*16 + l15
    #pragma unroll
    for (int n = 0; n < 2; ++n) {
        const int col = c0 + wn * 32 + n * 16 + l15;
        if (REMAP == 1) {
            const int which = col >> 10, cc = col & 1023;
            const float* bp_ = which == 0 ? bias0 : which == 1 ? bias1 : bias2;
            const float bv = bp_[cc];
            const int h = cc >> 6, d = cc & 63;
            #pragma unroll
            for (int f = 0; f < 8; ++f) {
                const int row0 = r0 + wm * 128 + f * 16 + quad * 4;
                const int b = row0 >> 11, t0 = row0 & (T_DIM - 1);
                if (which == 2) {
                    // V^T: vt[bh][d][t], 4 consecutive t -> one uint2 store
                    uint2 pk;
                    pk.x = pack2bf(acc[f][n][0] + bv, acc[f][n][1] + bv);
                    pk.y = pack2bf(acc[f][n][2] + bv, acc[f][n][3] + bv);
                    *(uint2*)&vtp[((size_t)((b * H_DIM + h) * HD + d)) * T_DIM + t0] = pk;
                } else {
                    #pragma unroll
                    for (int r = 0; r < 4; ++r) {
                        float val = acc[f][n][r] + bv;
                        if (which == 0) val *= QSCALE;
                        ((u16*)outp)[(size_t)which * NE +
                            (((size_t)(b * H_DIM + h) * T_DIM + (t0 + r)) * HD + d)] = f2bf(val);
                    }
                }
            }
        } else {
            const float bv = bias0[col];
            #pragma unroll
            for (int f = 0; f < 8; ++f) {
                #pragma unroll
                for (int r = 0; r < 4; ++r) {
                    const int row = r0 + wm * 128 + f * 16 + quad * 4 + r;
                    ((float*)outp)[(size_t)row * E_DIM + col] = acc[f][n][r] + bv;
                }
            }
        }
    }
}

// ---------------------------------------------------------------------------
// MFMA flash attention v6 (verified, unchanged): 32x32x16 MFMA, no P LDS
// round-trip (lane^32 exchange), max-free softmax, double-buffered K/V staging
// with XOR swizzles.
// ---------------------------------------------------------------------------
__global__ __launch_bounds__(256, 2)
void attn_kernel(const u16* __restrict__ q, const u16* __restrict__ k,
                 const u16* __restrict__ vt, u16* __restrict__ y)
{
    __shared__ u16 Ks[2][128 * 64];   // [key][d], 8 chunks/row, XOR-swizzled
    __shared__ u16 Vs[2][64 * 128];   // [d][key], 16 chunks/row, swizzled

    const int tid = threadIdx.x;
    const int w = tid >> 6, lane = tid & 63;
    const int hl = lane >> 5, l31 = lane & 31, l7 = lane & 7;
    const int bh = blockIdx.x;                    // XCD = bh % 8
    const int qt = gridDim.y - 1 - blockIdx.y;    // heavy q-blocks dispatch first
    const int q0 = qt * 128;
    const int b = bh >> 4, h = bh & (H_DIM - 1);
    const size_t qkb = (size_t)bh * (T_DIM * HD);
    const size_t vtb = (size_t)bh * (HD * T_DIM);

    // Q as B-operand: lane holds Q[d = kc*16 + hl*8 + j][query = q0+w*32+l31]
    const int qrow = q0 + w * 32 + l31;
    bf16x8 Qf[4];
    #pragma unroll
    for (int kc = 0; kc < 4; ++kc)
        Qf[kc] = ld_frag(&q[qkb + (size_t)qrow * HD + kc * 16 + hl * 8]);

    float rsum = 0.f;                 // row sum for query l31 (half-wave partial)
    floatx16 O[2];
    #pragma unroll
    for (int i = 0; i < 16; ++i) { O[0][i] = 0.f; O[1][i] = 0.f; }

    // stage K/V tile jt into buffer sel (async; fenced by next __syncthreads)
    auto stage = [&](int jt, int sel) {
        const int j0 = jt * 128;
        #pragma unroll
        for (int i = 0; i < 4; ++i) {
            const int L = i * 256 + tid;
            const unsigned off = __builtin_amdgcn_readfirstlane(i * 4096 + w * 1024);
            {   const int row = L >> 3, ch = (L & 7) ^ (row & 7);
                gl_lds16(&k[qkb + (size_t)(j0 + row) * HD + ch * 8],
                         (u16*)((char*)&Ks[sel][0] + off)); }
            {   const int row = L >> 4, ch = (L & 15) ^ (row & 7);
                gl_lds16(&vt[vtb + (size_t)row * T_DIM + j0 + ch * 8],
                         (u16*)((char*)&Vs[sel][0] + off)); }
        }
    };

    stage(0, 0);
    for (int jt = 0; jt <= qt; ++jt) {
        __syncthreads();                       // drains stage(jt)
        if (jt < qt) stage(jt + 1, (jt + 1) & 1);
        const u16* const Kb = &Ks[jt & 1][0];
        const u16* const Vb = &Vs[jt & 1][0];

        const bool diag = (jt == qt);
        const int nkg = diag ? (w + 1) : 4;    // active 32-key groups

        #pragma unroll
        for (int kg = 0; kg < 4; ++kg) {
            if (kg < nkg) {
                // S^T = K_kg @ Q : D[key=(reg&3)+8*(reg>>2)+4*hl][query=l31]
                floatx16 S;
                #pragma unroll
                for (int i = 0; i < 16; ++i) S[i] = 0.f;
                const int krow = kg * 32 + l31;
                #pragma unroll
                for (int kc = 0; kc < 4; ++kc) {
                    const int ch = (kc * 2 + hl) ^ l7;      // krow&7 == l7
                    S = __builtin_amdgcn_mfma_f32_32x32x16_bf16(
                            ld_frag(&Kb[krow * 64 + ch * 8]), Qf[kc], S, 0, 0, 0);
                }

                // exp2 (+ causal mask on boundary group), rsum, pack
                const bool bnd = diag && (kg == w);
                u32 u[8], ru[8];
                #pragma unroll
                for (int i = 0; i < 8; ++i) {
                    const int row0 = (2*i & 3) + 8 * (i >> 1) + 4 * hl;
                    float p0 = __builtin_amdgcn_exp2f(S[2*i]);
                    float p1 = __builtin_amdgcn_exp2f(S[2*i + 1]);
                    if (bnd && (row0     > l31)) p0 = 0.f;
                    if (bnd && (row0 + 1 > l31)) p1 = 0.f;
                    rsum += p0 + p1;
                    u[i] = pack2bf(p0, p1);
                }
                // lane^32 exchange: build PV A-frags (m=query=l31, k=keys)
                #pragma unroll
                for (int i = 0; i < 8; ++i) ru[i] = __shfl_xor(u[i], 32, 64);
                const u32x4 f0 = hl ? (u32x4){ru[2], ru[3], u[2], u[3]}
                                    : (u32x4){u[0], u[1], ru[0], ru[1]};
                const u32x4 f1 = hl ? (u32x4){ru[6], ru[7], u[6], u[7]}
                                    : (u32x4){u[4], u[5], ru[4], ru[5]};

                // O[dh] += P_chunk @ V  (B: lane = V[key=8*kc16+j][d=dh*32+l31])
                #pragma unroll
                for (int c2 = 0; c2 < 2; ++c2) {
                    const bf16x8 Pf = __builtin_bit_cast(bf16x8, c2 ? f1 : f0);
                    const int kc16 = kg * 4 + c2 * 2 + hl;
                    #pragma unroll
                    for (int dh = 0; dh < 2; ++dh) {
                        const int d = dh * 32 + l31;
                        const int ch = kc16 ^ l7;           // d&7 == l7
                        O[dh] = __builtin_amdgcn_mfma_f32_32x32x16_bf16(
                                    Pf, ld_frag(&Vb[d * 128 + ch * 8]), O[dh], 0, 0, 0);
                    }
                }
            }
        }
    }

    // epilogue: complete row sums (halves), normalize, store merged heads
    rsum += __shfl_xor(rsum, 32, 64);
    const float linv = 1.0f / rsum;            // for query l31
    #pragma unroll
    for (int i = 0; i < 16; ++i) {
        const int qr = (i & 3) + 8 * (i >> 2) + 4 * hl;    // query row of reg i
        const float lq = __shfl(linv, qr, 32);
        const int t = q0 + w * 32 + qr;
        const size_t base = ((size_t)(b * T_DIM + t)) * E_DIM + h * HD;
        y[base + l31]      = f2bf(O[0][i] * lq);
        y[base + 32 + l31] = f2bf(O[1][i] * lq);
    }
}

extern "C" void kernel_launch(void* const* d_in, const int* in_sizes, int n_in,
                              void* d_out, int out_size, void* d_ws, size_t ws_size,
                              hipStream_t stream)
{
    const float* x  = (const float*)d_in[0];
    const float* Wq = (const float*)d_in[2];
    const float* bq = (const float*)d_in[3];
    const float* Wk = (const float*)d_in[4];
    const float* bk = (const float*)d_in[5];
    const float* Wv = (const float*)d_in[6];
    const float* bv = (const float*)d_in[7];
    const float* Wp = (const float*)d_in[8];
    const float* bp = (const float*)d_in[9];

    u16* xb  = (u16*)d_ws;          // NE
    u16* wt  = xb + NE;             // 4*E2
    u16* qb  = wt + 4 * (size_t)E2; // NE (q) ; k at qb+NE
    u16* kb  = qb + NE;             // NE
    u16* vtb = kb + NE;             // NE  (V^T, written by the QKV GEMM)
    u16* yb  = vtb + NE;            // NE

    cvt_x_kernel<<<NE / (256 * 8), 256, 0, stream>>>(x, xb);
    transpose_cvt_kernel<<<dim3(16, 16, 4), 256, 0, stream>>>(Wq, Wk, Wv, Wp, wt);
    gemm256_kernel<1><<<768, 512, 0, stream>>>(xb, wt, bq, bk, bv, qb, vtb);
    attn_kernel<<<dim3(64, 16), 256, 0, stream>>>(qb, kb, vtb, yb);
    gemm256_kernel<0><<<256, 512, 0, stream>>>(yb, wt + 3 * (size_t)E2, bp, bp, bp, (float*)d_out, nullptr);
}

// Round 3
// 247.764 us; speedup vs baseline: 1.0644x; 1.0009x over previous
//
#include <hip/hip_runtime.h>
#include <cmath>

typedef unsigned short u16;
typedef unsigned int u32;
typedef __bf16 bf16x8 __attribute__((ext_vector_type(8)));
typedef float  floatx4 __attribute__((ext_vector_type(4)));
typedef float  floatx16 __attribute__((ext_vector_type(16)));
typedef unsigned int u32x4 __attribute__((ext_vector_type(4)));

#define T_DIM 2048
#define E_DIM 1024
#define H_DIM 16
#define HD    64
#define M_DIM 8192                    // B*T
#define NE    8388608                 // M*E  (also B*H*T*HD)
#define E2    1048576                 // E*E
#define QSCALE 0.18033688f            // 0.125 * log2(e): logits in exp2 domain

// float -> bf16 (RNE)
__device__ __forceinline__ u16 f2bf(float f) {
    unsigned u = __builtin_bit_cast(unsigned, f);
    return (u16)((u + 0x7FFFu + ((u >> 16) & 1u)) >> 16);
}
// two floats -> packed bf16x2
__device__ __forceinline__ u32 pack2bf(float f0, float f1) {
    u32 a0 = __builtin_bit_cast(u32, f0) + 0x8000u;
    u32 a1 = __builtin_bit_cast(u32, f1) + 0x8000u;
    return __builtin_amdgcn_perm(a1, a0, 0x07060302u);  // low16=bf(f0), high16=bf(f1)
}

// async global->LDS, 16B per lane. lds base wave-uniform; HW adds lane*16.
__device__ __forceinline__ void gl_lds16(const u16* g, const u16* l) {
    __builtin_amdgcn_global_load_lds(
        (const __attribute__((address_space(1))) void*)g,
        (__attribute__((address_space(3))) void*)l,
        16, 0, 0);
}

__device__ __forceinline__ bf16x8 ld_frag(const u16* p) {
    return *(const bf16x8*)p;
}

#define S_BARRIER()  asm volatile("s_barrier" ::: "memory")
#define WAIT_LGKM0() asm volatile("s_waitcnt lgkmcnt(0)" ::: "memory")

// ---------------------------------------------------------------------------
// x fp32 -> bf16, 8 elems/thread
// ---------------------------------------------------------------------------
__global__ void cvt_x_kernel(const float* __restrict__ x, u16* __restrict__ xb) {
    const size_t i = (size_t)blockIdx.x * 256 + threadIdx.x;
    const float4* s = (const float4*)x + i * 2;
    const float4 a = s[0], b = s[1];
    u16 v[8] __attribute__((aligned(16)));
    v[0]=f2bf(a.x); v[1]=f2bf(a.y); v[2]=f2bf(a.z); v[3]=f2bf(a.w);
    v[4]=f2bf(b.x); v[5]=f2bf(b.y); v[6]=f2bf(b.z); v[7]=f2bf(b.w);
    *(uint4*)(xb + i * 8) = *(const uint4*)v;
}

// ---------------------------------------------------------------------------
// W [K,N] fp32 -> Wt [N,K] bf16 (transpose+convert), 64x64 tiles.
// ---------------------------------------------------------------------------
__global__ void transpose_cvt_kernel(const float* __restrict__ w0, const float* __restrict__ w1,
                                     const float* __restrict__ w2, const float* __restrict__ w3,
                                     u16* __restrict__ out) {
    __shared__ u16 tile[64][65];
    const float* W = blockIdx.z == 0 ? w0 : blockIdx.z == 1 ? w1 : blockIdx.z == 2 ? w2 : w3;
    u16* O = out + (size_t)blockIdx.z * E2;
    const int k0 = blockIdx.y * 64, n0 = blockIdx.x * 64;
    const int r = threadIdx.x >> 2, cp = (threadIdx.x & 3) * 16;
    const float4* src = (const float4*)&W[(size_t)(k0 + r) * E_DIM + n0 + cp];
    #pragma unroll
    for (int j4 = 0; j4 < 4; ++j4) {
        const float4 f = src[j4];
        tile[r][cp + j4*4 + 0] = f2bf(f.x);
        tile[r][cp + j4*4 + 1] = f2bf(f.y);
        tile[r][cp + j4*4 + 2] = f2bf(f.z);
        tile[r][cp + j4*4 + 3] = f2bf(f.w);
    }
    __syncthreads();
    u16 vals[16] __attribute__((aligned(16)));
    #pragma unroll
    for (int j = 0; j < 16; ++j) vals[j] = tile[cp + j][r];
    u16* dst = &O[(size_t)(n0 + r) * E_DIM + k0 + cp];
    *(uint4*)dst       = *(const uint4*)vals;
    *(uint4*)(dst + 8) = *(const uint4*)(vals + 8);
}

// ---------------------------------------------------------------------------
// 256x128 BK=32 pipelined bf16 MFMA GEMM: out = A @ Bt^T + bias.
//
// 4 waves (2M x 2N, 256 thr), per-wave output 128x64 (m201's per-wave shape:
// 32 MFMA / 12 ds_read_b128 per K-tile = 43 FLOP per LDS byte).
// LDS 72 KiB = 3 rotating slots (A 3x16K, B 3x8K) -> 2 blocks/CU; the two
// co-resident blocks have INDEPENDENT barriers, so one block's waves absorb
// the other's barrier/lgkm stalls (round-2's 8-wave lockstep could not).
// Chunk-XOR swizzle for 4-chunk (64 B) rows: slot = chunk ^ (row&3), applied
// to global source + ds_read addr; bank-quad spread is exactly even.
// Per K-tile, 2 phases of 16 MFMA each:
//   P1: rd A-half0 (4 b128) + B (4) | stage A(kt+2) (4 gl_lds)
//       -> bar -> lgkm0 -> prio1 -> 16 MFMA -> prio0 -> bar
//   P2: rd A-half1 (4)              | stage B(kt+2) (2 gl_lds)
//       -> bar -> lgkm0 -> prio1 -> 16 MFMA -> prio0 -> vmcnt(6|0) -> bar
// Queue at end-P2(t): [A(t+1) 4, B(t+1) 2, A(t+2) 4, B(t+2) 2]; vmcnt(6)
// waits tile t+1 fully landed (needed at P1(t+1)); landing budget ~3.5
// phases >> HBM latency. vmcnt(0) only at kt==NT-2. Slot for t+2 equals
// slot of t-1; all reads of t-1 completed before end-P2(t-1) barrier.
// REMAP 0: fp32 out (out-proj). REMAP 1: bf16 q/k head-split (+QSCALE on q)
//   and V^T -> vt[bh][d][t] packed uint2.
// ---------------------------------------------------------------------------
#define NT 32   // K / BK = 1024 / 32

#define MFMA_PH(H)                                                              \
    _Pragma("unroll") for (int j = 0; j < 4; ++j)                               \
    _Pragma("unroll") for (int n = 0; n < 4; ++n)                               \
        acc[(H)*4 + j][n] = __builtin_amdgcn_mfma_f32_16x16x32_bf16(            \
            Aq[j], Bq[n], acc[(H)*4 + j][n], 0, 0, 0);

template<int REMAP>
__global__ __launch_bounds__(256, 2)
void gemm256_kernel(const u16* __restrict__ A, const u16* __restrict__ Bt,
                    const float* __restrict__ bias0, const float* __restrict__ bias1,
                    const float* __restrict__ bias2, void* __restrict__ outp,
                    u16* __restrict__ vtp)
{
    __shared__ u16 SM[36864];      // 72 KiB: A slots @0, B slots @byte 49152
    const int tid = threadIdx.x;
    const int w = tid >> 6, lane = tid & 63, quad = lane >> 4, l15 = lane & 15;
    const int wm = w >> 1, wn = w & 1;

    // XCD-chunked block swizzle (grids 768 / 256, both % 8 == 0)
    const int nbx = (REMAP == 1) ? 24 : 8;
    const int cpx = gridDim.x >> 3;
    const int swz = ((int)blockIdx.x & 7) * cpx + ((int)blockIdx.x >> 3);
    const int bx = swz % nbx, by = swz / nbx;
    const int r0 = by * 256, c0 = bx * 128;

    // staging source pointers (pre-swizzled): A 4 issues, B 2 issues
    const u16* pA[4]; const u16* pB[2];
    #pragma unroll
    for (int i = 0; i < 4; ++i) {
        const int L = i * 256 + tid, ra = L >> 2, ca = (L & 3) ^ (ra & 3);
        pA[i] = A + (size_t)(r0 + ra) * E_DIM + ca * 8;
    }
    #pragma unroll
    for (int i = 0; i < 2; ++i) {
        const int L = i * 256 + tid, rb = L >> 2, cb = (L & 3) ^ (rb & 3);
        pB[i] = Bt + (size_t)(c0 + rb) * E_DIM + cb * 8;
    }
    auto stageA = [&](int kt, int slot) {
        #pragma unroll
        for (int i = 0; i < 4; ++i) {
            const unsigned off = __builtin_amdgcn_readfirstlane(
                (unsigned)slot * 16384u + (unsigned)i * 4096u + (unsigned)w * 1024u);
            gl_lds16(pA[i] + kt * 32, (const u16*)((const char*)SM + off));
        }
    };
    auto stageB = [&](int kt, int slot) {
        #pragma unroll
        for (int i = 0; i < 2; ++i) {
            const unsigned off = __builtin_amdgcn_readfirstlane(
                49152u + (unsigned)slot * 8192u + (unsigned)i * 4096u + (unsigned)w * 1024u);
            gl_lds16(pB[i] + kt * 32, (const u16*)((const char*)SM + off));
        }
    };

    // fragment read offset: rows stride 32 u16; chunk slot = quad ^ (row&3),
    // and row&3 == l15&3 for all frag rows (multiples of 16 drop out).
    const int sl0 = (quad ^ (l15 & 3)) * 8;
    const int arow = (wm * 128 + l15) * 32;    // + j*512 per m-frag
    const int brow = (wn * 64 + l15) * 32;     // + n*512 per n-frag

    floatx4 acc[8][4];
    #pragma unroll
    for (int f = 0; f < 8; ++f)
        #pragma unroll
        for (int n = 0; n < 4; ++n) acc[f][n] = (floatx4){0.f, 0.f, 0.f, 0.f};

    bf16x8 Aq[4], Bq[4];

    // prologue: tiles 0,1 into slots 0,1 (12 loads); vmcnt(6) -> tile0 landed.
    stageA(0, 0); stageB(0, 0);
    stageA(1, 1); stageB(1, 1);
    asm volatile("s_waitcnt vmcnt(6)" ::: "memory");
    S_BARRIER();

    int scur = 0, sstg = 2;
    for (int kt = 0; kt < NT; ++kt) {
        const unsigned Au = (unsigned)scur * 8192u;            // u16 idx
        const unsigned Bu = 24576u + (unsigned)scur * 4096u;   // u16 idx

        // ---- P1: read A-half0 (4) + B (4); stage A(kt+2)
        #pragma unroll
        for (int j = 0; j < 4; ++j) Aq[j] = ld_frag(&SM[Au + arow + j * 512 + sl0]);
        #pragma unroll
        for (int n = 0; n < 4; ++n) Bq[n] = ld_frag(&SM[Bu + brow + n * 512 + sl0]);
        if (kt + 2 < NT) stageA(kt + 2, sstg);
        S_BARRIER(); WAIT_LGKM0();
        __builtin_amdgcn_s_setprio(1);
        MFMA_PH(0)
        __builtin_amdgcn_s_setprio(0);
        S_BARRIER();

        // ---- P2: read A-half1 (4); stage B(kt+2)
        #pragma unroll
        for (int j = 0; j < 4; ++j) Aq[j] = ld_frag(&SM[Au + arow + 2048 + j * 512 + sl0]);
        if (kt + 2 < NT) stageB(kt + 2, sstg);
        S_BARRIER(); WAIT_LGKM0();
        __builtin_amdgcn_s_setprio(1);
        MFMA_PH(1)
        __builtin_amdgcn_s_setprio(0);
        if (kt < NT - 2)       asm volatile("s_waitcnt vmcnt(6)" ::: "memory");
        else if (kt == NT - 2) asm volatile("s_waitcnt vmcnt(0)" ::: "memory");
        S_BARRIER();

        scur = scur == 2 ? 0 : scur + 1;
        sstg = sstg == 2 ? 0 : sstg + 1;
    }

    // epilogue: row = r0 + wm*128 + f*16 + quad*4 + r ; col = c0 + wn*64 + n*16 + l15
    #pragma unroll
    for (int n = 0; n < 4; ++n) {
        const int col = c0 + wn * 64 + n * 16 + l15;
        if (REMAP == 1) {
            const int which = col >> 10, cc = col & 1023;
            const float* bp_ = which == 0 ? bias0 : which == 1 ? bias1 : bias2;
            const float bv = bp_[cc];
            const int h = cc >> 6, d = cc & 63;
            #pragma unroll
            for (int f = 0; f < 8; ++f) {
                const int row0 = r0 + wm * 128 + f * 16 + quad * 4;
                const int b = row0 >> 11, t0 = row0 & (T_DIM - 1);
                if (which == 2) {
                    // V^T: vt[bh][d][t], 4 consecutive t -> one uint2 store
                    uint2 pk;
                    pk.x = pack2bf(acc[f][n][0] + bv, acc[f][n][1] + bv);
                    pk.y = pack2bf(acc[f][n][2] + bv, acc[f][n][3] + bv);
                    *(uint2*)&vtp[((size_t)((b * H_DIM + h) * HD + d)) * T_DIM + t0] = pk;
                } else {
                    #pragma unroll
                    for (int r = 0; r < 4; ++r) {
                        float val = acc[f][n][r] + bv;
                        if (which == 0) val *= QSCALE;
                        ((u16*)outp)[(size_t)which * NE +
                            (((size_t)(b * H_DIM + h) * T_DIM + (t0 + r)) * HD + d)] = f2bf(val);
                    }
                }
            }
        } else {
            const float bv = bias0[col];
            #pragma unroll
            for (int f = 0; f < 8; ++f) {
                #pragma unroll
                for (int r = 0; r < 4; ++r) {
                    const int row = r0 + wm * 128 + f * 16 + quad * 4 + r;
                    ((float*)outp)[(size_t)row * E_DIM + col] = acc[f][n][r] + bv;
                }
            }
        }
    }
}

// ---------------------------------------------------------------------------
// MFMA flash attention v6 (verified, unchanged): 32x32x16 MFMA, no P LDS
// round-trip (lane^32 exchange), max-free softmax, double-buffered K/V staging
// with XOR swizzles.
// ---------------------------------------------------------------------------
__global__ __launch_bounds__(256, 2)
void attn_kernel(const u16* __restrict__ q, const u16* __restrict__ k,
                 const u16* __restrict__ vt, u16* __restrict__ y)
{
    __shared__ u16 Ks[2][128 * 64];   // [key][d], 8 chunks/row, XOR-swizzled
    __shared__ u16 Vs[2][64 * 128];   // [d][key], 16 chunks/row, swizzled

    const int tid = threadIdx.x;
    const int w = tid >> 6, lane = tid & 63;
    const int hl = lane >> 5, l31 = lane & 31, l7 = lane & 7;
    const int bh = blockIdx.x;                    // XCD = bh % 8
    const int qt = gridDim.y - 1 - blockIdx.y;    // heavy q-blocks dispatch first
    const int q0 = qt * 128;
    const int b = bh >> 4, h = bh & (H_DIM - 1);
    const size_t qkb = (size_t)bh * (T_DIM * HD);
    const size_t vtb = (size_t)bh * (HD * T_DIM);

    // Q as B-operand: lane holds Q[d = kc*16 + hl*8 + j][query = q0+w*32+l31]
    const int qrow = q0 + w * 32 + l31;
    bf16x8 Qf[4];
    #pragma unroll
    for (int kc = 0; kc < 4; ++kc)
        Qf[kc] = ld_frag(&q[qkb + (size_t)qrow * HD + kc * 16 + hl * 8]);

    float rsum = 0.f;                 // row sum for query l31 (half-wave partial)
    floatx16 O[2];
    #pragma unroll
    for (int i = 0; i < 16; ++i) { O[0][i] = 0.f; O[1][i] = 0.f; }

    // stage K/V tile jt into buffer sel (async; fenced by next __syncthreads)
    auto stage = [&](int jt, int sel) {
        const int j0 = jt * 128;
        #pragma unroll
        for (int i = 0; i < 4; ++i) {
            const int L = i * 256 + tid;
            const unsigned off = __builtin_amdgcn_readfirstlane(i * 4096 + w * 1024);
            {   const int row = L >> 3, ch = (L & 7) ^ (row & 7);
                gl_lds16(&k[qkb + (size_t)(j0 + row) * HD + ch * 8],
                         (u16*)((char*)&Ks[sel][0] + off)); }
            {   const int row = L >> 4, ch = (L & 15) ^ (row & 7);
                gl_lds16(&vt[vtb + (size_t)row * T_DIM + j0 + ch * 8],
                         (u16*)((char*)&Vs[sel][0] + off)); }
        }
    };

    stage(0, 0);
    for (int jt = 0; jt <= qt; ++jt) {
        __syncthreads();                       // drains stage(jt)
        if (jt < qt) stage(jt + 1, (jt + 1) & 1);
        const u16* const Kb = &Ks[jt & 1][0];
        const u16* const Vb = &Vs[jt & 1][0];

        const bool diag = (jt == qt);
        const int nkg = diag ? (w + 1) : 4;    // active 32-key groups

        #pragma unroll
        for (int kg = 0; kg < 4; ++kg) {
            if (kg < nkg) {
                // S^T = K_kg @ Q : D[key=(reg&3)+8*(reg>>2)+4*hl][query=l31]
                floatx16 S;
                #pragma unroll
                for (int i = 0; i < 16; ++i) S[i] = 0.f;
                const int krow = kg * 32 + l31;
                #pragma unroll
                for (int kc = 0; kc < 4; ++kc) {
                    const int ch = (kc * 2 + hl) ^ l7;      // krow&7 == l7
                    S = __builtin_amdgcn_mfma_f32_32x32x16_bf16(
                            ld_frag(&Kb[krow * 64 + ch * 8]), Qf[kc], S, 0, 0, 0);
                }

                // exp2 (+ causal mask on boundary group), rsum, pack
                const bool bnd = diag && (kg == w);
                u32 u[8], ru[8];
                #pragma unroll
                for (int i = 0; i < 8; ++i) {
                    const int row0 = (2*i & 3) + 8 * (i >> 1) + 4 * hl;
                    float p0 = __builtin_amdgcn_exp2f(S[2*i]);
                    float p1 = __builtin_amdgcn_exp2f(S[2*i + 1]);
                    if (bnd && (row0     > l31)) p0 = 0.f;
                    if (bnd && (row0 + 1 > l31)) p1 = 0.f;
                    rsum += p0 + p1;
                    u[i] = pack2bf(p0, p1);
                }
                // lane^32 exchange: build PV A-frags (m=query=l31, k=keys)
                #pragma unroll
                for (int i = 0; i < 8; ++i) ru[i] = __shfl_xor(u[i], 32, 64);
                const u32x4 f0 = hl ? (u32x4){ru[2], ru[3], u[2], u[3]}
                                    : (u32x4){u[0], u[1], ru[0], ru[1]};
                const u32x4 f1 = hl ? (u32x4){ru[6], ru[7], u[6], u[7]}
                                    : (u32x4){u[4], u[5], ru[4], ru[5]};

                // O[dh] += P_chunk @ V  (B: lane = V[key=8*kc16+j][d=dh*32+l31])
                #pragma unroll
                for (int c2 = 0; c2 < 2; ++c2) {
                    const bf16x8 Pf = __builtin_bit_cast(bf16x8, c2 ? f1 : f0);
                    const int kc16 = kg * 4 + c2 * 2 + hl;
                    #pragma unroll
                    for (int dh = 0; dh < 2; ++dh) {
                        const int d = dh * 32 + l31;
                        const int ch = kc16 ^ l7;           // d&7 == l7
                        O[dh] = __builtin_amdgcn_mfma_f32_32x32x16_bf16(
                                    Pf, ld_frag(&Vb[d * 128 + ch * 8]), O[dh], 0, 0, 0);
                    }
                }
            }
        }
    }

    // epilogue: complete row sums (halves), normalize, store merged heads
    rsum += __shfl_xor(rsum, 32, 64);
    const float linv = 1.0f / rsum;            // for query l31
    #pragma unroll
    for (int i = 0; i < 16; ++i) {
        const int qr = (i & 3) + 8 * (i >> 2) + 4 * hl;    // query row of reg i
        const float lq = __shfl(linv, qr, 32);
        const int t = q0 + w * 32 + qr;
        const size_t base = ((size_t)(b * T_DIM + t)) * E_DIM + h * HD;
        y[base + l31]      = f2bf(O[0][i] * lq);
        y[base + 32 + l31] = f2bf(O[1][i] * lq);
    }
}

extern "C" void kernel_launch(void* const* d_in, const int* in_sizes, int n_in,
                              void* d_out, int out_size, void* d_ws, size_t ws_size,
                              hipStream_t stream)
{
    const float* x  = (const float*)d_in[0];
    const float* Wq = (const float*)d_in[2];
    const float* bq = (const float*)d_in[3];
    const float* Wk = (const float*)d_in[4];
    const float* bk = (const float*)d_in[5];
    const float* Wv = (const float*)d_in[6];
    const float* bv = (const float*)d_in[7];
    const float* Wp = (const float*)d_in[8];
    const float* bp = (const float*)d_in[9];

    u16* xb  = (u16*)d_ws;          // NE
    u16* wt  = xb + NE;             // 4*E2
    u16* qb  = wt + 4 * (size_t)E2; // NE (q) ; k at qb+NE
    u16* kb  = qb + NE;             // NE
    u16* vtb = kb + NE;             // NE  (V^T, written by the QKV GEMM)
    u16* yb  = vtb + NE;            // NE

    cvt_x_kernel<<<NE / (256 * 8), 256, 0, stream>>>(x, xb);
    transpose_cvt_kernel<<<dim3(16, 16, 4), 256, 0, stream>>>(Wq, Wk, Wv, Wp, wt);
    gemm256_kernel<1><<<768, 256, 0, stream>>>(xb, wt, bq, bk, bv, qb, vtb);
    attn_kernel<<<dim3(64, 16), 256, 0, stream>>>(qb, kb, vtb, yb);
    gemm256_kernel<0><<<256, 256, 0, stream>>>(yb, wt + 3 * (size_t)E2, bp, bp, bp, (float*)d_out, nullptr);
}

// Round 4
// 242.420 us; speedup vs baseline: 1.0878x; 1.0220x over previous
//
#include <hip/hip_runtime.h>
#include <cmath>

typedef unsigned short u16;
typedef unsigned int u32;
typedef __bf16 bf16x8 __attribute__((ext_vector_type(8)));
typedef float  floatx4 __attribute__((ext_vector_type(4)));
typedef float  floatx16 __attribute__((ext_vector_type(16)));
typedef unsigned int u32x4 __attribute__((ext_vector_type(4)));

#define T_DIM 2048
#define E_DIM 1024
#define H_DIM 16
#define HD    64
#define M_DIM 8192                    // B*T
#define NE    8388608                 // M*E  (also B*H*T*HD)
#define E2    1048576                 // E*E
#define QSCALE 0.18033688f            // 0.125 * log2(e): logits in exp2 domain

// float -> bf16 (RNE)
__device__ __forceinline__ u16 f2bf(float f) {
    unsigned u = __builtin_bit_cast(unsigned, f);
    return (u16)((u + 0x7FFFu + ((u >> 16) & 1u)) >> 16);
}
// two floats -> packed bf16x2
__device__ __forceinline__ u32 pack2bf(float f0, float f1) {
    u32 a0 = __builtin_bit_cast(u32, f0) + 0x8000u;
    u32 a1 = __builtin_bit_cast(u32, f1) + 0x8000u;
    return __builtin_amdgcn_perm(a1, a0, 0x07060302u);  // low16=bf(f0), high16=bf(f1)
}

// async global->LDS, 16B per lane. lds base wave-uniform; HW adds lane*16.
__device__ __forceinline__ void gl_lds16(const u16* g, const u16* l) {
    __builtin_amdgcn_global_load_lds(
        (const __attribute__((address_space(1))) void*)g,
        (__attribute__((address_space(3))) void*)l,
        16, 0, 0);
}

__device__ __forceinline__ bf16x8 ld_frag(const u16* p) {
    return *(const bf16x8*)p;
}

// ---------------------------------------------------------------------------
// Merged prep: blocks [0,4096) convert x fp32->bf16 (8 elems/thread);
// blocks [4096,5120) transpose+convert W [K,N] fp32 -> Wt [N,K] bf16.
// Both memory-bound; merging overlaps them and drops one launch gap.
// ---------------------------------------------------------------------------
__global__ void prep_kernel(const float* __restrict__ x, u16* __restrict__ xb,
                            const float* __restrict__ w0, const float* __restrict__ w1,
                            const float* __restrict__ w2, const float* __restrict__ w3,
                            u16* __restrict__ out) {
    __shared__ u16 tile[64][65];
    if (blockIdx.x < 4096) {
        const size_t i = (size_t)blockIdx.x * 256 + threadIdx.x;
        const float4* s = (const float4*)x + i * 2;
        const float4 a = s[0], b = s[1];
        u16 v[8] __attribute__((aligned(16)));
        v[0]=f2bf(a.x); v[1]=f2bf(a.y); v[2]=f2bf(a.z); v[3]=f2bf(a.w);
        v[4]=f2bf(b.x); v[5]=f2bf(b.y); v[6]=f2bf(b.z); v[7]=f2bf(b.w);
        *(uint4*)(xb + i * 8) = *(const uint4*)v;
        return;
    }
    const int bz2 = (int)blockIdx.x - 4096;
    const int z = bz2 >> 8, rem = bz2 & 255, byy = rem >> 4, bxx = rem & 15;
    const float* W = z == 0 ? w0 : z == 1 ? w1 : z == 2 ? w2 : w3;
    u16* O = out + (size_t)z * E2;
    const int k0 = byy * 64, n0 = bxx * 64;
    const int r = threadIdx.x >> 2, cp = (threadIdx.x & 3) * 16;
    const float4* src = (const float4*)&W[(size_t)(k0 + r) * E_DIM + n0 + cp];
    #pragma unroll
    for (int j4 = 0; j4 < 4; ++j4) {
        const float4 f = src[j4];
        tile[r][cp + j4*4 + 0] = f2bf(f.x);
        tile[r][cp + j4*4 + 1] = f2bf(f.y);
        tile[r][cp + j4*4 + 2] = f2bf(f.z);
        tile[r][cp + j4*4 + 3] = f2bf(f.w);
    }
    __syncthreads();
    u16 vals[16] __attribute__((aligned(16)));
    #pragma unroll
    for (int j = 0; j < 16; ++j) vals[j] = tile[cp + j][r];
    u16* dst = &O[(size_t)(n0 + r) * E_DIM + k0 + cp];
    *(uint4*)dst       = *(const uint4*)vals;
    *(uint4*)(dst + 8) = *(const uint4*)(vals + 8);
}

// ---------------------------------------------------------------------------
// bf16 MFMA GEMM, round-0 structure with BK=64 (barrier pairs halved 32->16):
// out = A @ Bt^T + bias. 128x128 tile, 4 waves (2x2), single-buffered LDS
// 32 KiB, per K-step: sync -> stage 8 gl_lds -> sync -> 2 x {read 8 frags,
// 16 MFMA}. Chunk-XOR swizzle for 8-chunk 128 B rows: slot = c ^ (row&7)
// on global source + ds_read (row&7 == l15&7 for all fragment rows).
// REMAP 0: fp32 out (out-proj).
// REMAP 1: bf16 head-split q/k (q gets QSCALE folded in) + V^T written
//          directly to vt[bh][d][t] (packed uint2, 4 consecutive t).
// ---------------------------------------------------------------------------
template<int REMAP>
__global__ __launch_bounds__(256)
void gemm_bf16_kernel(const u16* __restrict__ A, const u16* __restrict__ Bt,
                      const float* __restrict__ bias0, const float* __restrict__ bias1,
                      const float* __restrict__ bias2, void* __restrict__ outp,
                      u16* __restrict__ vtp)
{
    __shared__ __attribute__((aligned(16))) u16 As[128 * 64];
    __shared__ __attribute__((aligned(16))) u16 Bs[128 * 64];
    const int tid = threadIdx.x;
    const int w = tid >> 6, lane = tid & 63, quad = lane >> 4, l15 = lane & 15;
    const int wm = w >> 1, wn = w & 1;
    const int r0 = blockIdx.y * 128, c0 = blockIdx.x * 128;

    floatx4 acc[4][4];
    #pragma unroll
    for (int mi = 0; mi < 4; ++mi)
        #pragma unroll
        for (int ni = 0; ni < 4; ++ni)
            acc[mi][ni] = (floatx4){0.f, 0.f, 0.f, 0.f};

    // staging source pointers (pre-swizzled chunk): 4 issues each for A, B
    const u16* pA[4]; const u16* pB[4];
    #pragma unroll
    for (int i = 0; i < 4; ++i) {
        const int L = i * 256 + tid, row = L >> 3, s = L & 7, c = s ^ (row & 7);
        pA[i] = A  + (size_t)(r0 + row) * E_DIM + c * 8;
        pB[i] = Bt + (size_t)(c0 + row) * E_DIM + c * 8;
    }

    for (int k0 = 0; k0 < E_DIM; k0 += 64) {
        __syncthreads();
        #pragma unroll
        for (int i = 0; i < 4; ++i) {
            const unsigned off = __builtin_amdgcn_readfirstlane(i * 4096 + w * 1024);
            gl_lds16(pA[i] + k0, (u16*)((char*)As + off));
            gl_lds16(pB[i] + k0, (u16*)((char*)Bs + off));
        }
        __syncthreads();
        #pragma unroll
        for (int kk = 0; kk < 2; ++kk) {
            const int sl = ((kk * 4 + quad) ^ (l15 & 7)) * 8;   // swizzled chunk
            bf16x8 Af[4], Bf[4];
            #pragma unroll
            for (int mi = 0; mi < 4; ++mi) Af[mi] = ld_frag(&As[(wm*64 + mi*16 + l15) * 64 + sl]);
            #pragma unroll
            for (int ni = 0; ni < 4; ++ni) Bf[ni] = ld_frag(&Bs[(wn*64 + ni*16 + l15) * 64 + sl]);
            #pragma unroll
            for (int mi = 0; mi < 4; ++mi)
                #pragma unroll
                for (int ni = 0; ni < 4; ++ni)
                    acc[mi][ni] = __builtin_amdgcn_mfma_f32_16x16x32_bf16(Af[mi], Bf[ni], acc[mi][ni], 0, 0, 0);
        }
    }

    #pragma unroll
    for (int ni = 0; ni < 4; ++ni) {
        const int col = c0 + wn * 64 + ni * 16 + l15;
        float bv;
        int which = 0, cc = col;
        if (REMAP == 1) {
            which = col >> 10; cc = col & 1023;
            const float* bp_ = which == 0 ? bias0 : which == 1 ? bias1 : bias2;
            bv = bp_[cc];
        } else {
            bv = bias0[col];
        }
        #pragma unroll
        for (int mi = 0; mi < 4; ++mi) {
            if (REMAP == 1 && which == 2) {
                // V^T: vt[bh][d][t], 4 consecutive t -> one uint2 store
                const int h = cc >> 6, d = cc & 63;
                const int row0 = r0 + wm * 64 + mi * 16 + quad * 4;
                const int b = row0 >> 11, t0 = row0 & (T_DIM - 1);
                uint2 pk;
                pk.x = pack2bf(acc[mi][ni][0] + bv, acc[mi][ni][1] + bv);
                pk.y = pack2bf(acc[mi][ni][2] + bv, acc[mi][ni][3] + bv);
                *(uint2*)&vtp[((size_t)((b * H_DIM + h) * HD + d)) * T_DIM + t0] = pk;
            } else {
                #pragma unroll
                for (int r = 0; r < 4; ++r) {
                    const int row = r0 + wm * 64 + mi * 16 + quad * 4 + r;
                    float val = acc[mi][ni][r] + bv;
                    if (REMAP == 1) {
                        if (which == 0) val *= QSCALE;
                        const int h = cc >> 6, d = cc & 63;
                        const int b = row >> 11, t = row & (T_DIM - 1);
                        ((u16*)outp)[(size_t)which * NE +
                                     (((size_t)(b * H_DIM + h) * T_DIM + t) * HD + d)] = f2bf(val);
                    } else {
                        ((float*)outp)[(size_t)row * E_DIM + col] = val;
                    }
                }
            }
        }
    }
}

// ---------------------------------------------------------------------------
// MFMA flash attention v6 (verified, unchanged): 32x32x16 MFMA, no P LDS
// round-trip (lane^32 exchange), max-free softmax, double-buffered K/V staging
// with XOR swizzles.
// ---------------------------------------------------------------------------
__global__ __launch_bounds__(256, 2)
void attn_kernel(const u16* __restrict__ q, const u16* __restrict__ k,
                 const u16* __restrict__ vt, u16* __restrict__ y)
{
    __shared__ u16 Ks[2][128 * 64];   // [key][d], 8 chunks/row, XOR-swizzled
    __shared__ u16 Vs[2][64 * 128];   // [d][key], 16 chunks/row, swizzled

    const int tid = threadIdx.x;
    const int w = tid >> 6, lane = tid & 63;
    const int hl = lane >> 5, l31 = lane & 31, l7 = lane & 7;
    const int bh = blockIdx.x;                    // XCD = bh % 8
    const int qt = gridDim.y - 1 - blockIdx.y;    // heavy q-blocks dispatch first
    const int q0 = qt * 128;
    const int b = bh >> 4, h = bh & (H_DIM - 1);
    const size_t qkb = (size_t)bh * (T_DIM * HD);
    const size_t vtb = (size_t)bh * (HD * T_DIM);

    // Q as B-operand: lane holds Q[d = kc*16 + hl*8 + j][query = q0+w*32+l31]
    const int qrow = q0 + w * 32 + l31;
    bf16x8 Qf[4];
    #pragma unroll
    for (int kc = 0; kc < 4; ++kc)
        Qf[kc] = ld_frag(&q[qkb + (size_t)qrow * HD + kc * 16 + hl * 8]);

    float rsum = 0.f;                 // row sum for query l31 (half-wave partial)
    floatx16 O[2];
    #pragma unroll
    for (int i = 0; i < 16; ++i) { O[0][i] = 0.f; O[1][i] = 0.f; }

    // stage K/V tile jt into buffer sel (async; fenced by next __syncthreads)
    auto stage = [&](int jt, int sel) {
        const int j0 = jt * 128;
        #pragma unroll
        for (int i = 0; i < 4; ++i) {
            const int L = i * 256 + tid;
            const unsigned off = __builtin_amdgcn_readfirstlane(i * 4096 + w * 1024);
            {   const int row = L >> 3, ch = (L & 7) ^ (row & 7);
                gl_lds16(&k[qkb + (size_t)(j0 + row) * HD + ch * 8],
                         (u16*)((char*)&Ks[sel][0] + off)); }
            {   const int row = L >> 4, ch = (L & 15) ^ (row & 7);
                gl_lds16(&vt[vtb + (size_t)row * T_DIM + j0 + ch * 8],
                         (u16*)((char*)&Vs[sel][0] + off)); }
        }
    };

    stage(0, 0);
    for (int jt = 0; jt <= qt; ++jt) {
        __syncthreads();                       // drains stage(jt)
        if (jt < qt) stage(jt + 1, (jt + 1) & 1);
        const u16* const Kb = &Ks[jt & 1][0];
        const u16* const Vb = &Vs[jt & 1][0];

        const bool diag = (jt == qt);
        const int nkg = diag ? (w + 1) : 4;    // active 32-key groups

        #pragma unroll
        for (int kg = 0; kg < 4; ++kg) {
            if (kg < nkg) {
                // S^T = K_kg @ Q : D[key=(reg&3)+8*(reg>>2)+4*hl][query=l31]
                floatx16 S;
                #pragma unroll
                for (int i = 0; i < 16; ++i) S[i] = 0.f;
                const int krow = kg * 32 + l31;
                #pragma unroll
                for (int kc = 0; kc < 4; ++kc) {
                    const int ch = (kc * 2 + hl) ^ l7;      // krow&7 == l7
                    S = __builtin_amdgcn_mfma_f32_32x32x16_bf16(
                            ld_frag(&Kb[krow * 64 + ch * 8]), Qf[kc], S, 0, 0, 0);
                }

                // exp2 (+ causal mask on boundary group), rsum, pack
                const bool bnd = diag && (kg == w);
                u32 u[8], ru[8];
                #pragma unroll
                for (int i = 0; i < 8; ++i) {
                    const int row0 = (2*i & 3) + 8 * (i >> 1) + 4 * hl;
                    float p0 = __builtin_amdgcn_exp2f(S[2*i]);
                    float p1 = __builtin_amdgcn_exp2f(S[2*i + 1]);
                    if (bnd && (row0     > l31)) p0 = 0.f;
                    if (bnd && (row0 + 1 > l31)) p1 = 0.f;
                    rsum += p0 + p1;
                    u[i] = pack2bf(p0, p1);
                }
                // lane^32 exchange: build PV A-frags (m=query=l31, k=keys)
                #pragma unroll
                for (int i = 0; i < 8; ++i) ru[i] = __shfl_xor(u[i], 32, 64);
                const u32x4 f0 = hl ? (u32x4){ru[2], ru[3], u[2], u[3]}
                                    : (u32x4){u[0], u[1], ru[0], ru[1]};
                const u32x4 f1 = hl ? (u32x4){ru[6], ru[7], u[6], u[7]}
                                    : (u32x4){u[4], u[5], ru[4], ru[5]};

                // O[dh] += P_chunk @ V  (B: lane = V[key=8*kc16+j][d=dh*32+l31])
                #pragma unroll
                for (int c2 = 0; c2 < 2; ++c2) {
                    const bf16x8 Pf = __builtin_bit_cast(bf16x8, c2 ? f1 : f0);
                    const int kc16 = kg * 4 + c2 * 2 + hl;
                    #pragma unroll
                    for (int dh = 0; dh < 2; ++dh) {
                        const int d = dh * 32 + l31;
                        const int ch = kc16 ^ l7;           // d&7 == l7
                        O[dh] = __builtin_amdgcn_mfma_f32_32x32x16_bf16(
                                    Pf, ld_frag(&Vb[d * 128 + ch * 8]), O[dh], 0, 0, 0);
                    }
                }
            }
        }
    }

    // epilogue: complete row sums (halves), normalize, store merged heads
    rsum += __shfl_xor(rsum, 32, 64);
    const float linv = 1.0f / rsum;            // for query l31
    #pragma unroll
    for (int i = 0; i < 16; ++i) {
        const int qr = (i & 3) + 8 * (i >> 2) + 4 * hl;    // query row of reg i
        const float lq = __shfl(linv, qr, 32);
        const int t = q0 + w * 32 + qr;
        const size_t base = ((size_t)(b * T_DIM + t)) * E_DIM + h * HD;
        y[base + l31]      = f2bf(O[0][i] * lq);
        y[base + 32 + l31] = f2bf(O[1][i] * lq);
    }
}

extern "C" void kernel_launch(void* const* d_in, const int* in_sizes, int n_in,
                              void* d_out, int out_size, void* d_ws, size_t ws_size,
                              hipStream_t stream)
{
    const float* x  = (const float*)d_in[0];
    const float* Wq = (const float*)d_in[2];
    const float* bq = (const float*)d_in[3];
    const float* Wk = (const float*)d_in[4];
    const float* bk = (const float*)d_in[5];
    const float* Wv = (const float*)d_in[6];
    const float* bv = (const float*)d_in[7];
    const float* Wp = (const float*)d_in[8];
    const float* bp = (const float*)d_in[9];

    u16* xb  = (u16*)d_ws;          // NE
    u16* wt  = xb + NE;             // 4*E2
    u16* qb  = wt + 4 * (size_t)E2; // NE (q) ; k at qb+NE
    u16* kb  = qb + NE;             // NE
    u16* vtb = kb + NE;             // NE  (V^T, written by the QKV GEMM)
    u16* yb  = vtb + NE;            // NE

    prep_kernel<<<5120, 256, 0, stream>>>(x, xb, Wq, Wk, Wv, Wp, wt);
    gemm_bf16_kernel<1><<<dim3(24, 64), 256, 0, stream>>>(xb, wt, bq, bk, bv, qb, vtb);
    attn_kernel<<<dim3(64, 16), 256, 0, stream>>>(qb, kb, vtb, yb);
    gemm_bf16_kernel<0><<<dim3(8, 64), 256, 0, stream>>>(yb, wt + 3 * (size_t)E2, bp, bp, bp, (float*)d_out, nullptr);
}